// Round 6
// baseline (124.870 us; speedup 1.0000x reference)
//
#include <hip/hip_runtime.h>
#include <hip/hip_bf16.h>
#include <math.h>

#define BB 64
#define SS 400
#define F2H 512
#define HID 256
#define EMB 128
#define NGATE 1024
#define VOC 50000
#define CH 64
#define NCHK 7

typedef short bf16x8 __attribute__((ext_vector_type(8)));
typedef float f32x4 __attribute__((ext_vector_type(4)));

__device__ __forceinline__ float sigm(float x) { return 1.0f / (1.0f + __expf(-x)); }

__device__ __forceinline__ float ftanh(float x) {
    x = fminf(fmaxf(x, -15.0f), 15.0f);
    float t = __expf(2.0f * x);
    return (t - 1.0f) / (t + 1.0f);
}

__device__ __forceinline__ ushort f2bf(float x) {
    uint32_t u = __float_as_uint(x);
    uint32_t r = u + 0x7FFFu + ((u >> 16) & 1u);
    return (ushort)(r >> 16);
}

// packed fp32x8 -> bf16x8 via v_cvt_pk_bf16_f32
__device__ __forceinline__ bf16x8 cvt8(float4 a, float4 b) {
    __hip_bfloat162 p0 = __float22bfloat162_rn({a.x, a.y});
    __hip_bfloat162 p1 = __float22bfloat162_rn({a.z, a.w});
    __hip_bfloat162 p2 = __float22bfloat162_rn({b.x, b.y});
    __hip_bfloat162 p3 = __float22bfloat162_rn({b.z, b.w});
    union { bf16x8 v; uint32_t u[4]; } r;
    r.u[0] = *(uint32_t*)&p0;
    r.u[1] = *(uint32_t*)&p1;
    r.u[2] = *(uint32_t*)&p2;
    r.u[3] = *(uint32_t*)&p3;
    return r.v;
}

// ---------------- K1a: gates partial GEMM + fused wenc prep ----------------
__global__ __launch_bounds__(256) void k_gates(
    const int* __restrict__ word, const float* __restrict__ hidden,
    const float* __restrict__ embed, const float* __restrict__ W_ih,
    const float* __restrict__ W_hh, float* __restrict__ part,
    const float* __restrict__ attn_W, ushort* __restrict__ wenc_bf)
{
    const int gt = blockIdx.x;
    const int ks = blockIdx.y;
    const int tid = threadIdx.x;

    if (ks == 4) {   // wenc prep
        int i0 = gt * 2048 + tid;
#pragma unroll
        for (int r = 0; r < 8; ++r) {
            int i = i0 + r * 256;
            int row = i >> 7, c = i & 127;
            float4 f = *(const float4*)&attn_W[row * 768 + c * 4];
            ushort4 o = make_ushort4(f2bf(f.x), f2bf(f.y), f2bf(f.z), f2bf(f.w));
            ((ushort4*)wenc_bf)[i] = o;
        }
        return;
    }

    __shared__ float As[32 * 68];
    __shared__ float Bs[32 * 68];
    const int g0 = gt * 64;
    const int k0 = ks * 96;
    float acc[4][4];
#pragma unroll
    for (int i = 0; i < 4; ++i)
#pragma unroll
        for (int j = 0; j < 4; ++j) acc[i][j] = 0.0f;

    const int tb = tid >> 4;
    const int tg = tid & 15;
    const int srow = tid >> 3;
    const int skk = (tid & 7) * 4;

    for (int c = 0; c < 3; ++c) {
        const int kc = k0 + c * 32;
#pragma unroll
        for (int p = 0; p < 2; ++p) {
            int rr = srow + p * 32;
            int gk = kc + skk;
            float4 f;
            if (gk < EMB) {
                int w = word[rr];
                f = *(const float4*)&embed[w * EMB + gk];
            } else {
                f = *(const float4*)&hidden[rr * HID + gk - EMB];
            }
            As[(skk + 0) * 68 + rr] = f.x;
            As[(skk + 1) * 68 + rr] = f.y;
            As[(skk + 2) * 68 + rr] = f.z;
            As[(skk + 3) * 68 + rr] = f.w;
        }
#pragma unroll
        for (int p = 0; p < 2; ++p) {
            int nn = srow + p * 32;
            int g = g0 + nn;
            int gk = kc + skk;
            float4 f;
            if (gk < EMB) f = *(const float4*)&W_ih[g * EMB + gk];
            else          f = *(const float4*)&W_hh[g * HID + gk - EMB];
            Bs[(skk + 0) * 68 + nn] = f.x;
            Bs[(skk + 1) * 68 + nn] = f.y;
            Bs[(skk + 2) * 68 + nn] = f.z;
            Bs[(skk + 3) * 68 + nn] = f.w;
        }
        __syncthreads();
#pragma unroll 8
        for (int k = 0; k < 32; ++k) {
            float4 a = *(const float4*)&As[k * 68 + tb * 4];
            float4 b = *(const float4*)&Bs[k * 68 + tg * 4];
            float av[4] = {a.x, a.y, a.z, a.w};
            float bv[4] = {b.x, b.y, b.z, b.w};
#pragma unroll
            for (int i = 0; i < 4; ++i)
#pragma unroll
                for (int j = 0; j < 4; ++j) acc[i][j] += av[i] * bv[j];
        }
        __syncthreads();
    }
    float* dst = part + ks * (BB * NGATE);
#pragma unroll
    for (int i = 0; i < 4; ++i) {
        int b = tb * 4 + i;
        float4 o = {acc[i][0], acc[i][1], acc[i][2], acc[i][3]};
        *(float4*)&dst[b * NGATE + g0 + tg * 4] = o;
    }
}

// ---------------- K1b: LSTM pointwise + hproj ----------------
__global__ __launch_bounds__(256) void k_lstm(
    const float* __restrict__ part, const float* __restrict__ cell,
    const float* __restrict__ b_ih, const float* __restrict__ b_hh,
    const float* __restrict__ attn_W, const float* __restrict__ attn_b,
    float* __restrict__ h_out, float* __restrict__ c_out, float* __restrict__ hproj)
{
    const int b = blockIdx.x;
    const int u = threadIdx.x;
    __shared__ float hrow[HID];

    float gi = b_ih[u] + b_hh[u];
    float gf = b_ih[u + 256] + b_hh[u + 256];
    float gg = b_ih[u + 512] + b_hh[u + 512];
    float go = b_ih[u + 768] + b_hh[u + 768];
#pragma unroll
    for (int ks = 0; ks < 4; ++ks) {
        const float* p = part + ks * (BB * NGATE) + b * NGATE;
        gi += p[u];
        gf += p[u + 256];
        gg += p[u + 512];
        go += p[u + 768];
    }
    float c = sigm(gf) * cell[b * HID + u] + sigm(gi) * tanhf(gg);
    float h = tanhf(sigm(go) * tanhf(c));
    c_out[b * HID + u] = c;
    h_out[b * HID + u] = h;
    hrow[u] = h;
    __syncthreads();

    float acc = attn_b[u];
    const float* wr = attn_W + u * 768 + 512;
#pragma unroll 8
    for (int k = 0; k < HID; k += 4) {
        float4 w = *(const float4*)&wr[k];
        acc += hrow[k] * w.x + hrow[k + 1] * w.y + hrow[k + 2] * w.z + hrow[k + 3] * w.w;
    }
    hproj[b * HID + u] = acc;
}

// ---------------- K2: fused attention, register-direct (no LDS GEMM, no K-loop barriers) ----------------
// grid = 64 b x 7 chunks of 64 s; 256 threads = 4 waves (wave: 32 rows x 128 cols)
__global__ __launch_bounds__(256) void k_attn(
    const float* __restrict__ enc, const ushort* __restrict__ wenc_bf,
    const float* __restrict__ hproj, const float* __restrict__ vvec,
    float* __restrict__ ctxp, float* __restrict__ mls)
{
    const int b   = blockIdx.x / NCHK;
    const int chk = blockIdx.x % NCHK;
    const int s0  = chk * CH;
    const int tid = threadIdx.x;
    const int l = tid & 63;
    const int w = tid >> 6;
    const int wr = w >> 1, wc = w & 1;
    const int brow0 = b * SS;
    const int ln = l & 15, q = l >> 4;

    __shared__ float epart[CH][2];
    __shared__ float ps[CH];

    // A fragment pointers: row clamped (garbage rows masked in epilogue)
    const float* aptr[2];
#pragma unroll
    for (int mf = 0; mf < 2; ++mf) {
        int r = s0 + wr * 32 + mf * 16 + ln;
        if (r >= SS) r = SS - 1;
        aptr[mf] = enc + (size_t)(brow0 + r) * F2H + q * 8;
    }
    // B fragment pointers (wenc L2-resident)
    const ushort* bptr[8];
#pragma unroll
    for (int nf = 0; nf < 8; ++nf)
        bptr[nf] = wenc_bf + (size_t)(wc * 128 + nf * 16 + ln) * F2H + q * 8;

    f32x4 acc[2][8];
#pragma unroll
    for (int mf = 0; mf < 2; ++mf)
#pragma unroll
        for (int nf = 0; nf < 8; ++nf) acc[mf][nf] = (f32x4){0.f, 0.f, 0.f, 0.f};

#pragma unroll
    for (int it = 0; it < 16; ++it) {
        const int ko = it * 32;           // folds to imm offsets
        bf16x8 af[2], bfr[8];
#pragma unroll
        for (int mf = 0; mf < 2; ++mf) {
            float4 a0 = *(const float4*)(aptr[mf] + ko);
            float4 a1 = *(const float4*)(aptr[mf] + ko + 4);
            af[mf] = cvt8(a0, a1);
        }
#pragma unroll
        for (int nf = 0; nf < 8; ++nf)
            bfr[nf] = *(const bf16x8*)(bptr[nf] + ko);
#pragma unroll
        for (int mf = 0; mf < 2; ++mf)
#pragma unroll
            for (int nf = 0; nf < 8; ++nf)
                acc[mf][nf] = __builtin_amdgcn_mfma_f32_16x16x32_bf16(
                    af[mf], bfr[nf], acc[mf][nf], 0, 0, 0);
    }

    // epilogue: + hproj, tanh, dot v, 16-lane reduce
    float vv[8];
#pragma unroll
    for (int nf = 0; nf < 8; ++nf) vv[nf] = vvec[wc * 128 + nf * 16 + ln];
    const float* hp = hproj + b * HID;

#pragma unroll
    for (int mf = 0; mf < 2; ++mf) {
#pragma unroll
        for (int r = 0; r < 4; ++r) {
            int row = wr * 32 + mf * 16 + q * 4 + r;
            float p = 0.0f;
#pragma unroll
            for (int nf = 0; nf < 8; ++nf) {
                int col = wc * 128 + nf * 16 + ln;
                p += vv[nf] * ftanh(acc[mf][nf][r] + hp[col]);
            }
#pragma unroll
            for (int off = 8; off >= 1; off >>= 1) p += __shfl_xor(p, off);
            if (ln == 0) epart[row][wc] = p;
        }
    }
    __syncthreads();

    // chunk softmax partial (one wave)
    if (tid < 64) {
        int s = s0 + tid;
        float es = (s < SS) ? (epart[tid][0] + epart[tid][1]) : -1e30f;
        float m = es;
#pragma unroll
        for (int off = 32; off >= 1; off >>= 1) m = fmaxf(m, __shfl_xor(m, off));
        float p = __expf(es - m);
        ps[tid] = p;
        float sum = p;
#pragma unroll
        for (int off = 32; off >= 1; off >>= 1) sum += __shfl_xor(sum, off);
        if (tid == 0) {
            mls[(b * NCHK + chk) * 2 + 0] = m;
            mls[(b * NCHK + chk) * 2 + 1] = sum;
        }
    }
    __syncthreads();

    // chunk context partial
    const float* ep = enc + (size_t)(brow0 + s0) * F2H;
    const int smax = (SS - s0 < CH) ? (SS - s0) : CH;
    float c0 = 0.f, c1 = 0.f;
    for (int s = 0; s < smax; s += 4) {
#pragma unroll
        for (int q2 = 0; q2 < 4; ++q2) {
            float p = ps[s + q2];
            c0 += p * ep[(size_t)(s + q2) * F2H + tid];
            c1 += p * ep[(size_t)(s + q2) * F2H + tid + 256];
        }
    }
    ctxp[(size_t)(b * NCHK + chk) * F2H + tid] = c0;
    ctxp[(size_t)(b * NCHK + chk) * F2H + tid + 256] = c1;
}

// ---------------- K3: combine chunks + concat + projection ----------------
__global__ __launch_bounds__(256) void k_comb(
    const float* __restrict__ ctxp, const float* __restrict__ mls,
    const float* __restrict__ hvals, const float* __restrict__ proj_W,
    const float* __restrict__ proj_b, float* __restrict__ catp)
{
    const int b = blockIdx.x;
    const int j = threadIdx.x;
    __shared__ float cat[768];

    float m[NCHK], lv[NCHK];
#pragma unroll
    for (int c = 0; c < NCHK; ++c) {
        m[c]  = mls[(b * NCHK + c) * 2 + 0];
        lv[c] = mls[(b * NCHK + c) * 2 + 1];
    }
    float ms = m[0];
#pragma unroll
    for (int c = 1; c < NCHK; ++c) ms = fmaxf(ms, m[c]);
    float wgt[NCHK], L = 0.f;
#pragma unroll
    for (int c = 0; c < NCHK; ++c) { wgt[c] = __expf(m[c] - ms); L += lv[c] * wgt[c]; }
    float inv = 1.0f / L;

#pragma unroll
    for (int p = 0; p < 2; ++p) {
        int f = j + p * 256;
        float s = 0.f;
#pragma unroll
        for (int c = 0; c < NCHK; ++c) s += ctxp[((size_t)(b * NCHK + c)) * F2H + f] * wgt[c];
        cat[f] = s * inv;
    }
    cat[F2H + j] = hvals[b * HID + j];
    __syncthreads();

    float acc = proj_b[j];
    const float* wr = proj_W + j * 768;
#pragma unroll 8
    for (int k = 0; k < 768; k += 4) {
        float4 wv = *(const float4*)&wr[k];
        acc += cat[k] * wv.x + cat[k + 1] * wv.y + cat[k + 2] * wv.z + cat[k + 3] * wv.w;
    }
    catp[b * HID + j] = acc;
}

// ---------------- K6: output GEMM via bf16 MFMA, v-tile 64, register-direct B ----------------
// grid 782; 256 thr = 4 waves; wave: 16 v x 64 b
__global__ __launch_bounds__(256) void k_out(
    const float* __restrict__ catp, const float* __restrict__ out_W,
    const float* __restrict__ out_b, float* __restrict__ wd)
{
    __shared__ ushort Cs[64 * 256];   // catp bf16, swizzled

    const int tid = threadIdx.x;
    const int l = tid & 63;
    const int w = tid >> 6;
    const int q = l >> 4;
    const int ln = l & 15;

    // stage catp (64 rows x 256 k) -> bf16 swizzled LDS
#pragma unroll
    for (int i = 0; i < 8; ++i) {
        int u = i * 256 + tid;
        int n = u >> 5, c16 = u & 31;
        const float4* src = (const float4*)&catp[n * HID + c16 * 8];
        float4 f0 = src[0], f1 = src[1];
        *(bf16x8*)&Cs[n * 256 + ((c16 ^ (n & 7)) * 8)] = cvt8(f0, f1);
    }
    __syncthreads();

    const int v = blockIdx.x * 64 + w * 16 + ln;
    const int vr = v < VOC ? v : VOC - 1;
    const float* pw = out_W + (size_t)vr * HID + q * 8;

    f32x4 acc[4];
#pragma unroll
    for (int af = 0; af < 4; ++af) acc[af] = (f32x4){0.f, 0.f, 0.f, 0.f};

#pragma unroll
    for (int s = 0; s < 8; ++s) {
        float4 b0 = *(const float4*)(pw + s * 32);
        float4 b1 = *(const float4*)(pw + s * 32 + 4);
        bf16x8 bfr = cvt8(b0, b1);
#pragma unroll
        for (int af = 0; af < 4; ++af) {
            int row = af * 16 + ln;
            int c16 = (s * 4 + q) ^ (row & 7);
            bf16x8 a = *(const bf16x8*)&Cs[row * 256 + c16 * 8];
            acc[af] = __builtin_amdgcn_mfma_f32_16x16x32_bf16(a, bfr, acc[af], 0, 0, 0);
        }
    }

    if (v < VOC) {
        float bias = out_b[v];
#pragma unroll
        for (int af = 0; af < 4; ++af) {
            int b = af * 16 + q * 4;
#pragma unroll
            for (int r = 0; r < 4; ++r)
                wd[(size_t)(b + r) * VOC + v] = acc[af][r] + bias;
        }
    }
}

extern "C" void kernel_launch(void* const* d_in, const int* in_sizes, int n_in,
                              void* d_out, int out_size, void* d_ws, size_t ws_size,
                              hipStream_t stream) {
    const int*   word   = (const int*)  d_in[0];
    const float* hidden = (const float*)d_in[1];
    const float* cell   = (const float*)d_in[2];
    const float* enc    = (const float*)d_in[3];
    const float* embed  = (const float*)d_in[5];
    const float* W_ih   = (const float*)d_in[6];
    const float* W_hh   = (const float*)d_in[7];
    const float* b_ih   = (const float*)d_in[8];
    const float* b_hh   = (const float*)d_in[9];
    const float* attn_W = (const float*)d_in[10];
    const float* attn_b = (const float*)d_in[11];
    const float* vvec   = (const float*)d_in[12];
    const float* proj_W = (const float*)d_in[13];
    const float* proj_b = (const float*)d_in[14];
    const float* out_W  = (const float*)d_in[15];
    const float* out_b  = (const float*)d_in[16];

    float* wd  = (float*)d_out;
    float* h_o = wd + (size_t)BB * VOC;
    float* c_o = h_o + BB * HID;

    float* ws    = (float*)d_ws;
    float* part  = ws;                          // 262144
    float* hproj = part + 262144;               // 16384
    float* catp  = hproj + 16384;               // 16384
    float* ctxp  = catp + 16384;                // 64*7*512 = 229376
    float* mls   = ctxp + 229376;               // 896
    ushort* wenc_bf = (ushort*)(mls + 896);     // 131072 ushorts

    k_gates<<<dim3(16, 5), 256, 0, stream>>>(word, hidden, embed, W_ih, W_hh, part, attn_W, wenc_bf);
    k_lstm<<<64, 256, 0, stream>>>(part, cell, b_ih, b_hh, attn_W, attn_b, h_o, c_o, hproj);
    k_attn<<<BB * NCHK, 256, 0, stream>>>(enc, wenc_bf, hproj, vvec, ctxp, mls);
    k_comb<<<64, 256, 0, stream>>>(ctxp, mls, h_o, proj_W, proj_b, catp);
    k_out<<<782, 256, 0, stream>>>(catp, out_W, out_b, wd);
}

// Round 7
// 94.894 us; speedup vs baseline: 1.3159x; 1.3159x over previous
//
#include <hip/hip_runtime.h>
#include <hip/hip_bf16.h>
#include <math.h>

#define BB 64
#define SS 400
#define F2H 512
#define HID 256
#define EMB 128
#define NGATE 1024
#define VOC 50000
#define CH 32
#define NCHK 13
#define KC 32
#define NKC 16

typedef short bf16x8 __attribute__((ext_vector_type(8)));
typedef float f32x4 __attribute__((ext_vector_type(4)));

__device__ __forceinline__ float sigm(float x) { return 1.0f / (1.0f + __expf(-x)); }

__device__ __forceinline__ float ftanh(float x) {
    x = fminf(fmaxf(x, -15.0f), 15.0f);
    float t = __expf(2.0f * x);
    return (t - 1.0f) / (t + 1.0f);
}

__device__ __forceinline__ ushort f2bf(float x) {
    uint32_t u = __float_as_uint(x);
    uint32_t r = u + 0x7FFFu + ((u >> 16) & 1u);
    return (ushort)(r >> 16);
}

__device__ __forceinline__ bf16x8 cvt8(float4 a, float4 b) {
    __hip_bfloat162 p0 = __float22bfloat162_rn({a.x, a.y});
    __hip_bfloat162 p1 = __float22bfloat162_rn({a.z, a.w});
    __hip_bfloat162 p2 = __float22bfloat162_rn({b.x, b.y});
    __hip_bfloat162 p3 = __float22bfloat162_rn({b.z, b.w});
    union { bf16x8 v; uint32_t u[4]; } r;
    r.u[0] = *(uint32_t*)&p0;
    r.u[1] = *(uint32_t*)&p1;
    r.u[2] = *(uint32_t*)&p2;
    r.u[3] = *(uint32_t*)&p3;
    return r.v;
}

__device__ __forceinline__ uint2 cvt4(float4 a) {
    __hip_bfloat162 p0 = __float22bfloat162_rn({a.x, a.y});
    __hip_bfloat162 p1 = __float22bfloat162_rn({a.z, a.w});
    uint2 r;
    r.x = *(uint32_t*)&p0;
    r.y = *(uint32_t*)&p1;
    return r;
}

// ---------------- K1a: gates partial GEMM + fused wenc prep ----------------
__global__ __launch_bounds__(256) void k_gates(
    const int* __restrict__ word, const float* __restrict__ hidden,
    const float* __restrict__ embed, const float* __restrict__ W_ih,
    const float* __restrict__ W_hh, float* __restrict__ part,
    const float* __restrict__ attn_W, ushort* __restrict__ wenc_bf)
{
    const int gt = blockIdx.x;
    const int ks = blockIdx.y;
    const int tid = threadIdx.x;

    if (ks == 4) {   // wenc prep
        int i0 = gt * 2048 + tid;
#pragma unroll
        for (int r = 0; r < 8; ++r) {
            int i = i0 + r * 256;
            int row = i >> 7, c = i & 127;
            float4 f = *(const float4*)&attn_W[row * 768 + c * 4];
            ushort4 o = make_ushort4(f2bf(f.x), f2bf(f.y), f2bf(f.z), f2bf(f.w));
            ((ushort4*)wenc_bf)[i] = o;
        }
        return;
    }

    __shared__ float As[32 * 68];
    __shared__ float Bs[32 * 68];
    const int g0 = gt * 64;
    const int k0 = ks * 96;
    float acc[4][4];
#pragma unroll
    for (int i = 0; i < 4; ++i)
#pragma unroll
        for (int j = 0; j < 4; ++j) acc[i][j] = 0.0f;

    const int tb = tid >> 4;
    const int tg = tid & 15;
    const int srow = tid >> 3;
    const int skk = (tid & 7) * 4;

    for (int c = 0; c < 3; ++c) {
        const int kc = k0 + c * 32;
#pragma unroll
        for (int p = 0; p < 2; ++p) {
            int rr = srow + p * 32;
            int gk = kc + skk;
            float4 f;
            if (gk < EMB) {
                int w = word[rr];
                f = *(const float4*)&embed[w * EMB + gk];
            } else {
                f = *(const float4*)&hidden[rr * HID + gk - EMB];
            }
            As[(skk + 0) * 68 + rr] = f.x;
            As[(skk + 1) * 68 + rr] = f.y;
            As[(skk + 2) * 68 + rr] = f.z;
            As[(skk + 3) * 68 + rr] = f.w;
        }
#pragma unroll
        for (int p = 0; p < 2; ++p) {
            int nn = srow + p * 32;
            int g = g0 + nn;
            int gk = kc + skk;
            float4 f;
            if (gk < EMB) f = *(const float4*)&W_ih[g * EMB + gk];
            else          f = *(const float4*)&W_hh[g * HID + gk - EMB];
            Bs[(skk + 0) * 68 + nn] = f.x;
            Bs[(skk + 1) * 68 + nn] = f.y;
            Bs[(skk + 2) * 68 + nn] = f.z;
            Bs[(skk + 3) * 68 + nn] = f.w;
        }
        __syncthreads();
#pragma unroll 8
        for (int k = 0; k < 32; ++k) {
            float4 a = *(const float4*)&As[k * 68 + tb * 4];
            float4 b = *(const float4*)&Bs[k * 68 + tg * 4];
            float av[4] = {a.x, a.y, a.z, a.w};
            float bv[4] = {b.x, b.y, b.z, b.w};
#pragma unroll
            for (int i = 0; i < 4; ++i)
#pragma unroll
                for (int j = 0; j < 4; ++j) acc[i][j] += av[i] * bv[j];
        }
        __syncthreads();
    }
    float* dst = part + ks * (BB * NGATE);
#pragma unroll
    for (int i = 0; i < 4; ++i) {
        int b = tb * 4 + i;
        float4 o = {acc[i][0], acc[i][1], acc[i][2], acc[i][3]};
        *(float4*)&dst[b * NGATE + g0 + tg * 4] = o;
    }
}

// ---------------- K1b: LSTM pointwise + hproj ----------------
__global__ __launch_bounds__(256) void k_lstm(
    const float* __restrict__ part, const float* __restrict__ cell,
    const float* __restrict__ b_ih, const float* __restrict__ b_hh,
    const float* __restrict__ attn_W, const float* __restrict__ attn_b,
    float* __restrict__ h_out, float* __restrict__ c_out, float* __restrict__ hproj)
{
    const int b = blockIdx.x;
    const int u = threadIdx.x;
    __shared__ float hrow[HID];

    float gi = b_ih[u] + b_hh[u];
    float gf = b_ih[u + 256] + b_hh[u + 256];
    float gg = b_ih[u + 512] + b_hh[u + 512];
    float go = b_ih[u + 768] + b_hh[u + 768];
#pragma unroll
    for (int ks = 0; ks < 4; ++ks) {
        const float* p = part + ks * (BB * NGATE) + b * NGATE;
        gi += p[u];
        gf += p[u + 256];
        gg += p[u + 512];
        go += p[u + 768];
    }
    float c = sigm(gf) * cell[b * HID + u] + sigm(gi) * tanhf(gg);
    float h = tanhf(sigm(go) * tanhf(c));
    c_out[b * HID + u] = c;
    h_out[b * HID + u] = h;
    hrow[u] = h;
    __syncthreads();

    float acc = attn_b[u];
    const float* wr = attn_W + u * 768 + 512;
#pragma unroll 8
    for (int k = 0; k < HID; k += 4) {
        float4 w = *(const float4*)&wr[k];
        acc += hrow[k] * w.x + hrow[k + 1] * w.y + hrow[k + 2] * w.z + hrow[k + 3] * w.w;
    }
    hproj[b * HID + u] = acc;
}

// ---------------- K2: fused attention, LDS-staged, CH=32 for TLP ----------------
// grid = 64 b x 13 chunks of 32 s; 256 threads = 4 waves (wave: 32 rows x 64 cols)
__global__ __launch_bounds__(256) void k_attn(
    const float* __restrict__ enc, const ushort* __restrict__ wenc_bf,
    const float* __restrict__ hproj, const float* __restrict__ vvec,
    float* __restrict__ ctxp, float* __restrict__ mls)
{
    const int b   = blockIdx.x / NCHK;
    const int chk = blockIdx.x % NCHK;
    const int s0  = chk * CH;
    const int tid = threadIdx.x;
    const int l = tid & 63;
    const int w = tid >> 6;
    const int brow0 = b * SS;
    const int ln = l & 15, q = l >> 4;

    __shared__ ushort Asm[2][CH * 40];     // pad stride 40
    __shared__ ushort Bsm[2][256 * KC];    // unit-XOR swizzled
    __shared__ float epart[CH][4];
    __shared__ float ps[CH];

    // A stage mapping: 256 thr = 32 rows x 8 col-units of 4 floats
    const int arow = tid >> 3;
    const int acolu = tid & 7;
    const int srow = s0 + arow;
    const bool aval = srow < SS;
    const float* abase = enc + (size_t)(brow0 + (aval ? srow : SS - 1)) * F2H + acolu * 4;
    const int busrc = ((l & 3) ^ ((l >> 3) & 3)) * 8;

    f32x4 acc[2][4];
#pragma unroll
    for (int mf = 0; mf < 2; ++mf)
#pragma unroll
        for (int nf = 0; nf < 4; ++nf) acc[mf][nf] = (f32x4){0.f, 0.f, 0.f, 0.f};

    // prologue: stage chunk 0 -> buf 0
    {
#pragma unroll
        for (int i = 0; i < 4; ++i) {
            int j = w * 4 + i;
            int row = j * 16 + (l >> 2);
            const ushort* src = wenc_bf + (size_t)row * F2H + busrc;
            __builtin_amdgcn_global_load_lds(
                (const __attribute__((address_space(1))) uint32_t*)src,
                (__attribute__((address_space(3))) uint32_t*)(&Bsm[0][j * 512]),
                16, 0, 0);
        }
        float4 a0 = *(const float4*)abase;
        *(uint2*)&Asm[0][arow * 40 + acolu * 4] = cvt4(a0);
    }
    __syncthreads();

    int buf = 0;
    for (int it = 0; it < NKC; ++it) {
        const int nkc = (it + 1) * KC;
        const bool pf = (it + 1) < NKC;
        float4 a0;
        if (pf) {
            a0 = *(const float4*)(abase + nkc);
#pragma unroll
            for (int i = 0; i < 4; ++i) {
                int j = w * 4 + i;
                int row = j * 16 + (l >> 2);
                const ushort* src = wenc_bf + (size_t)row * F2H + nkc + busrc;
                __builtin_amdgcn_global_load_lds(
                    (const __attribute__((address_space(1))) uint32_t*)src,
                    (__attribute__((address_space(3))) uint32_t*)(&Bsm[buf ^ 1][j * 512]),
                    16, 0, 0);
            }
        }
        // compute on buf
        bf16x8 af[2], bfr[4];
#pragma unroll
        for (int mf = 0; mf < 2; ++mf) {
            int row = mf * 16 + ln;
            af[mf] = *(const bf16x8*)&Asm[buf][row * 40 + q * 8];
        }
#pragma unroll
        for (int nf = 0; nf < 4; ++nf) {
            int row = w * 64 + nf * 16 + ln;
            int u = q ^ ((l >> 1) & 3);
            bfr[nf] = *(const bf16x8*)&Bsm[buf][row * KC + u * 8];
        }
#pragma unroll
        for (int mf = 0; mf < 2; ++mf)
#pragma unroll
            for (int nf = 0; nf < 4; ++nf)
                acc[mf][nf] = __builtin_amdgcn_mfma_f32_16x16x32_bf16(
                    af[mf], bfr[nf], acc[mf][nf], 0, 0, 0);
        if (pf) {
            *(uint2*)&Asm[buf ^ 1][arow * 40 + acolu * 4] = cvt4(a0);
        }
        __syncthreads();
        buf ^= 1;
    }

    // epilogue: + hproj, tanh, dot v, 16-lane reduce; wave covers cols w*64..+63
    float vv[4];
#pragma unroll
    for (int nf = 0; nf < 4; ++nf) vv[nf] = vvec[w * 64 + nf * 16 + ln];
    const float* hp = hproj + b * HID;

#pragma unroll
    for (int mf = 0; mf < 2; ++mf) {
#pragma unroll
        for (int r = 0; r < 4; ++r) {
            int row = mf * 16 + q * 4 + r;
            float p = 0.0f;
#pragma unroll
            for (int nf = 0; nf < 4; ++nf) {
                int col = w * 64 + nf * 16 + ln;
                p += vv[nf] * ftanh(acc[mf][nf][r] + hp[col]);
            }
#pragma unroll
            for (int off = 8; off >= 1; off >>= 1) p += __shfl_xor(p, off);
            if (ln == 0) epart[row][w] = p;
        }
    }
    __syncthreads();

    // chunk softmax partial over 32 rows (lanes 0..31 of wave 0)
    if (tid < 32) {
        int s = s0 + tid;
        float es = (s < SS)
            ? ((epart[tid][0] + epart[tid][1]) + (epart[tid][2] + epart[tid][3]))
            : -1e30f;
        float m = es;
#pragma unroll
        for (int off = 16; off >= 1; off >>= 1) m = fmaxf(m, __shfl_xor(m, off));
        float p = __expf(es - m);
        ps[tid] = p;
        float sum = p;
#pragma unroll
        for (int off = 16; off >= 1; off >>= 1) sum += __shfl_xor(sum, off);
        if (tid == 0) {
            mls[(b * NCHK + chk) * 2 + 0] = m;
            mls[(b * NCHK + chk) * 2 + 1] = sum;
        }
    }
    __syncthreads();

    // chunk context partial
    const float* ep = enc + (size_t)(brow0 + s0) * F2H;
    const int smax = (SS - s0 < CH) ? (SS - s0) : CH;
    float c0 = 0.f, c1 = 0.f;
    for (int s = 0; s < smax; s += 4) {
#pragma unroll
        for (int q2 = 0; q2 < 4; ++q2) {
            float p = ps[s + q2];
            c0 += p * ep[(size_t)(s + q2) * F2H + tid];
            c1 += p * ep[(size_t)(s + q2) * F2H + tid + 256];
        }
    }
    ctxp[(size_t)(b * NCHK + chk) * F2H + tid] = c0;
    ctxp[(size_t)(b * NCHK + chk) * F2H + tid + 256] = c1;
}

// ---------------- K3: combine chunks + concat + projection ----------------
__global__ __launch_bounds__(256) void k_comb(
    const float* __restrict__ ctxp, const float* __restrict__ mls,
    const float* __restrict__ hvals, const float* __restrict__ proj_W,
    const float* __restrict__ proj_b, float* __restrict__ catp)
{
    const int b = blockIdx.x;
    const int j = threadIdx.x;
    __shared__ float cat[768];

    float m[NCHK], lv[NCHK];
#pragma unroll
    for (int c = 0; c < NCHK; ++c) {
        m[c]  = mls[(b * NCHK + c) * 2 + 0];
        lv[c] = mls[(b * NCHK + c) * 2 + 1];
    }
    float ms = m[0];
#pragma unroll
    for (int c = 1; c < NCHK; ++c) ms = fmaxf(ms, m[c]);
    float wgt[NCHK], L = 0.f;
#pragma unroll
    for (int c = 0; c < NCHK; ++c) { wgt[c] = __expf(m[c] - ms); L += lv[c] * wgt[c]; }
    float inv = 1.0f / L;

#pragma unroll
    for (int p = 0; p < 2; ++p) {
        int f = j + p * 256;
        float s = 0.f;
#pragma unroll
        for (int c = 0; c < NCHK; ++c) s += ctxp[((size_t)(b * NCHK + c)) * F2H + f] * wgt[c];
        cat[f] = s * inv;
    }
    cat[F2H + j] = hvals[b * HID + j];
    __syncthreads();

    float acc = proj_b[j];
    const float* wr = proj_W + j * 768;
#pragma unroll 8
    for (int k = 0; k < 768; k += 4) {
        float4 wv = *(const float4*)&wr[k];
        acc += cat[k] * wv.x + cat[k + 1] * wv.y + cat[k + 2] * wv.z + cat[k + 3] * wv.w;
    }
    catp[b * HID + j] = acc;
}

// ---------------- K6: output GEMM, v-tile 64, full-row B preload ----------------
// grid 782; 256 thr = 4 waves; wave: 16 v x 64 b
__global__ __launch_bounds__(256) void k_out(
    const float* __restrict__ catp, const float* __restrict__ out_W,
    const float* __restrict__ out_b, float* __restrict__ wd)
{
    __shared__ ushort Cs[64 * 256];   // catp bf16, swizzled

    const int tid = threadIdx.x;
    const int l = tid & 63;
    const int w = tid >> 6;
    const int q = l >> 4;
    const int ln = l & 15;

    const int v = blockIdx.x * 64 + w * 16 + ln;
    const int vr = v < VOC ? v : VOC - 1;
    const float* pw = out_W + (size_t)vr * HID + q * 8;

    // issue ALL out_W loads first (16 x float4 in flight, hides HBM latency)
    float4 wreg[16];
#pragma unroll
    for (int s = 0; s < 8; ++s) {
        wreg[2 * s]     = *(const float4*)(pw + s * 32);
        wreg[2 * s + 1] = *(const float4*)(pw + s * 32 + 4);
    }

    // stage catp (64 rows x 256 k) -> bf16 swizzled LDS
#pragma unroll
    for (int i = 0; i < 8; ++i) {
        int u = i * 256 + tid;
        int n = u >> 5, c16 = u & 31;
        const float4* src = (const float4*)&catp[n * HID + c16 * 8];
        float4 f0 = src[0], f1 = src[1];
        *(bf16x8*)&Cs[n * 256 + ((c16 ^ (n & 7)) * 8)] = cvt8(f0, f1);
    }
    __syncthreads();

    f32x4 acc[4];
#pragma unroll
    for (int af = 0; af < 4; ++af) acc[af] = (f32x4){0.f, 0.f, 0.f, 0.f};

#pragma unroll
    for (int s = 0; s < 8; ++s) {
        bf16x8 bfr = cvt8(wreg[2 * s], wreg[2 * s + 1]);
#pragma unroll
        for (int af = 0; af < 4; ++af) {
            int row = af * 16 + ln;
            int c16 = (s * 4 + q) ^ (row & 7);
            bf16x8 a = *(const bf16x8*)&Cs[row * 256 + c16 * 8];
            acc[af] = __builtin_amdgcn_mfma_f32_16x16x32_bf16(a, bfr, acc[af], 0, 0, 0);
        }
    }

    if (v < VOC) {
        float bias = out_b[v];
#pragma unroll
        for (int af = 0; af < 4; ++af) {
            int b = af * 16 + q * 4;
#pragma unroll
            for (int r = 0; r < 4; ++r)
                wd[(size_t)(b + r) * VOC + v] = acc[af][r] + bias;
        }
    }
}

extern "C" void kernel_launch(void* const* d_in, const int* in_sizes, int n_in,
                              void* d_out, int out_size, void* d_ws, size_t ws_size,
                              hipStream_t stream) {
    const int*   word   = (const int*)  d_in[0];
    const float* hidden = (const float*)d_in[1];
    const float* cell   = (const float*)d_in[2];
    const float* enc    = (const float*)d_in[3];
    const float* embed  = (const float*)d_in[5];
    const float* W_ih   = (const float*)d_in[6];
    const float* W_hh   = (const float*)d_in[7];
    const float* b_ih   = (const float*)d_in[8];
    const float* b_hh   = (const float*)d_in[9];
    const float* attn_W = (const float*)d_in[10];
    const float* attn_b = (const float*)d_in[11];
    const float* vvec   = (const float*)d_in[12];
    const float* proj_W = (const float*)d_in[13];
    const float* proj_b = (const float*)d_in[14];
    const float* out_W  = (const float*)d_in[15];
    const float* out_b  = (const float*)d_in[16];

    float* wd  = (float*)d_out;
    float* h_o = wd + (size_t)BB * VOC;
    float* c_o = h_o + BB * HID;

    float* ws    = (float*)d_ws;
    float* part  = ws;                          // 262144
    float* hproj = part + 262144;               // 16384
    float* catp  = hproj + 16384;               // 16384
    float* ctxp  = catp + 16384;                // 64*13*512 = 425984
    float* mls   = ctxp + 425984;               // 1664
    ushort* wenc_bf = (ushort*)(mls + 1664);    // 131072 ushorts

    k_gates<<<dim3(16, 5), 256, 0, stream>>>(word, hidden, embed, W_ih, W_hh, part, attn_W, wenc_bf);
    k_lstm<<<64, 256, 0, stream>>>(part, cell, b_ih, b_hh, attn_W, attn_b, h_o, c_o, hproj);
    k_attn<<<BB * NCHK, 256, 0, stream>>>(enc, wenc_bf, hproj, vvec, ctxp, mls);
    k_comb<<<64, 256, 0, stream>>>(ctxp, mls, h_o, proj_W, proj_b, catp);
    k_out<<<782, 256, 0, stream>>>(catp, out_W, out_b, wd);
}

// Round 8
// 93.542 us; speedup vs baseline: 1.3349x; 1.0145x over previous
//
#include <hip/hip_runtime.h>
#include <hip/hip_bf16.h>
#include <math.h>

#define BB 64
#define SS 400
#define F2H 512
#define HID 256
#define EMB 128
#define NGATE 1024
#define VOC 50000
#define CH 64
#define NCHK 7
#define KC 32
#define NKC 16

typedef short bf16x8 __attribute__((ext_vector_type(8)));
typedef float f32x4 __attribute__((ext_vector_type(4)));

__device__ __forceinline__ float sigm(float x) { return 1.0f / (1.0f + __expf(-x)); }

__device__ __forceinline__ float ftanh(float x) {
    x = fminf(fmaxf(x, -15.0f), 15.0f);
    float t = __expf(2.0f * x);
    return (t - 1.0f) / (t + 1.0f);
}

__device__ __forceinline__ ushort f2bf(float x) {
    uint32_t u = __float_as_uint(x);
    uint32_t r = u + 0x7FFFu + ((u >> 16) & 1u);
    return (ushort)(r >> 16);
}

__device__ __forceinline__ bf16x8 cvt8(float4 a, float4 b) {
    __hip_bfloat162 p0 = __float22bfloat162_rn({a.x, a.y});
    __hip_bfloat162 p1 = __float22bfloat162_rn({a.z, a.w});
    __hip_bfloat162 p2 = __float22bfloat162_rn({b.x, b.y});
    __hip_bfloat162 p3 = __float22bfloat162_rn({b.z, b.w});
    union { bf16x8 v; uint32_t u[4]; } r;
    r.u[0] = *(uint32_t*)&p0;
    r.u[1] = *(uint32_t*)&p1;
    r.u[2] = *(uint32_t*)&p2;
    r.u[3] = *(uint32_t*)&p3;
    return r.v;
}

// ---------------- K1a: gates partial GEMM + fused wenc prep ----------------
__global__ __launch_bounds__(256) void k_gates(
    const int* __restrict__ word, const float* __restrict__ hidden,
    const float* __restrict__ embed, const float* __restrict__ W_ih,
    const float* __restrict__ W_hh, float* __restrict__ part,
    const float* __restrict__ attn_W, ushort* __restrict__ wenc_bf)
{
    const int gt = blockIdx.x;
    const int ks = blockIdx.y;
    const int tid = threadIdx.x;

    if (ks == 4) {   // wenc prep
        int i0 = gt * 2048 + tid;
#pragma unroll
        for (int r = 0; r < 8; ++r) {
            int i = i0 + r * 256;
            int row = i >> 7, c = i & 127;
            float4 f = *(const float4*)&attn_W[row * 768 + c * 4];
            ushort4 o = make_ushort4(f2bf(f.x), f2bf(f.y), f2bf(f.z), f2bf(f.w));
            ((ushort4*)wenc_bf)[i] = o;
        }
        return;
    }

    __shared__ float As[32 * 68];
    __shared__ float Bs[32 * 68];
    const int g0 = gt * 64;
    const int k0 = ks * 96;
    float acc[4][4];
#pragma unroll
    for (int i = 0; i < 4; ++i)
#pragma unroll
        for (int j = 0; j < 4; ++j) acc[i][j] = 0.0f;

    const int tb = tid >> 4;
    const int tg = tid & 15;
    const int srow = tid >> 3;
    const int skk = (tid & 7) * 4;

    for (int c = 0; c < 3; ++c) {
        const int kc = k0 + c * 32;
#pragma unroll
        for (int p = 0; p < 2; ++p) {
            int rr = srow + p * 32;
            int gk = kc + skk;
            float4 f;
            if (gk < EMB) {
                int w = word[rr];
                f = *(const float4*)&embed[w * EMB + gk];
            } else {
                f = *(const float4*)&hidden[rr * HID + gk - EMB];
            }
            As[(skk + 0) * 68 + rr] = f.x;
            As[(skk + 1) * 68 + rr] = f.y;
            As[(skk + 2) * 68 + rr] = f.z;
            As[(skk + 3) * 68 + rr] = f.w;
        }
#pragma unroll
        for (int p = 0; p < 2; ++p) {
            int nn = srow + p * 32;
            int g = g0 + nn;
            int gk = kc + skk;
            float4 f;
            if (gk < EMB) f = *(const float4*)&W_ih[g * EMB + gk];
            else          f = *(const float4*)&W_hh[g * HID + gk - EMB];
            Bs[(skk + 0) * 68 + nn] = f.x;
            Bs[(skk + 1) * 68 + nn] = f.y;
            Bs[(skk + 2) * 68 + nn] = f.z;
            Bs[(skk + 3) * 68 + nn] = f.w;
        }
        __syncthreads();
#pragma unroll 8
        for (int k = 0; k < 32; ++k) {
            float4 a = *(const float4*)&As[k * 68 + tb * 4];
            float4 b = *(const float4*)&Bs[k * 68 + tg * 4];
            float av[4] = {a.x, a.y, a.z, a.w};
            float bv[4] = {b.x, b.y, b.z, b.w};
#pragma unroll
            for (int i = 0; i < 4; ++i)
#pragma unroll
                for (int j = 0; j < 4; ++j) acc[i][j] += av[i] * bv[j];
        }
        __syncthreads();
    }
    float* dst = part + ks * (BB * NGATE);
#pragma unroll
    for (int i = 0; i < 4; ++i) {
        int b = tb * 4 + i;
        float4 o = {acc[i][0], acc[i][1], acc[i][2], acc[i][3]};
        *(float4*)&dst[b * NGATE + g0 + tg * 4] = o;
    }
}

// ---------------- K1b: LSTM pointwise + hproj ----------------
__global__ __launch_bounds__(256) void k_lstm(
    const float* __restrict__ part, const float* __restrict__ cell,
    const float* __restrict__ b_ih, const float* __restrict__ b_hh,
    const float* __restrict__ attn_W, const float* __restrict__ attn_b,
    float* __restrict__ h_out, float* __restrict__ c_out, float* __restrict__ hproj)
{
    const int b = blockIdx.x;
    const int u = threadIdx.x;
    __shared__ float hrow[HID];

    float gi = b_ih[u] + b_hh[u];
    float gf = b_ih[u + 256] + b_hh[u + 256];
    float gg = b_ih[u + 512] + b_hh[u + 512];
    float go = b_ih[u + 768] + b_hh[u + 768];
#pragma unroll
    for (int ks = 0; ks < 4; ++ks) {
        const float* p = part + ks * (BB * NGATE) + b * NGATE;
        gi += p[u];
        gf += p[u + 256];
        gg += p[u + 512];
        go += p[u + 768];
    }
    float c = sigm(gf) * cell[b * HID + u] + sigm(gi) * tanhf(gg);
    float h = tanhf(sigm(go) * tanhf(c));
    c_out[b * HID + u] = c;
    h_out[b * HID + u] = h;
    hrow[u] = h;
    __syncthreads();

    float acc = attn_b[u];
    const float* wr = attn_W + u * 768 + 512;
#pragma unroll 8
    for (int k = 0; k < HID; k += 4) {
        float4 w = *(const float4*)&wr[k];
        acc += hrow[k] * w.x + hrow[k + 1] * w.y + hrow[k + 2] * w.z + hrow[k + 3] * w.w;
    }
    hproj[b * HID + u] = acc;
}

// ---------------- K2: fused attention, counted-vmcnt software pipeline ----------------
// grid = 64 b x 7 chunks of 64 s; 256 threads = 4 waves (wave: 32 rows x 128 cols)
// A (enc) loads issued 3 iters ahead into rotating regs; B gloadlds 2 ahead into
// a 3-buffer LDS ring; s_waitcnt vmcnt(12) per iter (never 0 in loop); raw s_barrier.
__global__ __launch_bounds__(256) void k_attn(
    const float* __restrict__ enc, const ushort* __restrict__ wenc_bf,
    const float* __restrict__ hproj, const float* __restrict__ vvec,
    float* __restrict__ ctxp, float* __restrict__ mls)
{
    const int b   = blockIdx.x / NCHK;
    const int chk = blockIdx.x % NCHK;
    const int s0  = chk * CH;
    const int tid = threadIdx.x;
    const int l = tid & 63;
    const int w = tid >> 6;
    const int wr = w >> 1, wc = w & 1;
    const int brow0 = b * SS;
    const int ln = l & 15, q = l >> 4;

    __shared__ ushort Asm[2][CH * 40];     // 10 KB, pad stride 40 (2-way max)
    __shared__ ushort Bsm[3][256 * KC];    // 48 KB ring
    __shared__ float epart[CH][2];
    __shared__ float ps[CH];

    // A staging map: thread -> row tid>>2 (4 thr/row), col unit tid&3 (8 floats)
    const int arow = tid >> 2;
    const int aunit = tid & 3;
    const int srow = s0 + arow;
    const float* abase = enc + (size_t)(brow0 + (srow < SS ? srow : SS - 1)) * F2H + aunit * 8;
    // B gloadlds: per wave 4 issues; j-group j=w*4+i covers rows j*16..+15
    const int brow_l = l >> 2;                         // row within j-group
    const int bunit  = (l & 3) ^ ((l >> 3) & 3);       // pre-swizzled source unit
    const int aswz   = arow * 40 + aunit * 8;          // LDS ushort offset for A

    f32x4 acc[2][8];
#pragma unroll
    for (int mf = 0; mf < 2; ++mf)
#pragma unroll
        for (int nf = 0; nf < 8; ++nf) acc[mf][nf] = (f32x4){0.f, 0.f, 0.f, 0.f};

    float4 regA[3][2];

#define ISSUE_A(t) do { \
        regA[(t) % 3][0] = *(const float4*)(abase + ((t) + 3) * KC); \
        regA[(t) % 3][1] = *(const float4*)(abase + ((t) + 3) * KC + 4); \
    } while (0)
#define ISSUE_B(dstbuf, kk) do { \
        _Pragma("unroll") \
        for (int i = 0; i < 4; ++i) { \
            int j = w * 4 + i; \
            int row = j * 16 + brow_l; \
            const ushort* src = wenc_bf + (size_t)row * F2H + (kk) * KC + bunit * 8; \
            __builtin_amdgcn_global_load_lds( \
                (const __attribute__((address_space(1))) uint32_t*)src, \
                (__attribute__((address_space(3))) uint32_t*)(&Bsm[dstbuf][j * 512]), \
                16, 0, 0); \
        } \
    } while (0)

    // prologue: A(0),A(1),A(2) -> regA[0,1,2]; B(0)->buf0, B(1)->buf1
    {
        regA[0][0] = *(const float4*)(abase + 0);
        regA[0][1] = *(const float4*)(abase + 4);
        regA[1][0] = *(const float4*)(abase + KC);
        regA[1][1] = *(const float4*)(abase + KC + 4);
        regA[2][0] = *(const float4*)(abase + 2 * KC);
        regA[2][1] = *(const float4*)(abase + 2 * KC + 4);
        ISSUE_B(0, 0);
        ISSUE_B(1, 1);
        __builtin_amdgcn_sched_barrier(0);
        asm volatile("s_waitcnt vmcnt(12)" ::: "memory");   // A(0) done
        __builtin_amdgcn_sched_barrier(0);
        *(bf16x8*)&Asm[0][aswz] = cvt8(regA[0][0], regA[0][1]);
    }

#pragma unroll
    for (int t = 0; t < NKC; ++t) {
        // step1: issue stage for t+3 (A) / t+2 (B)
        if (t <= NKC - 4) ISSUE_A(t);
        if (t <= NKC - 3) ISSUE_B((t + 2) % 3, t + 2);
        __builtin_amdgcn_sched_barrier(0);
        // step2: counted drain — batch(t-2) complete; keep newest 2 batches in flight
        if (t == 0)           asm volatile("s_waitcnt vmcnt(10)" ::: "memory");
        else if (t <= 12)     asm volatile("s_waitcnt vmcnt(12)" ::: "memory");
        else if (t == 13)     asm volatile("s_waitcnt vmcnt(10)" ::: "memory");
        else if (t == 14)     asm volatile("s_waitcnt vmcnt(4)"  ::: "memory");
        else                  asm volatile("s_waitcnt vmcnt(0)"  ::: "memory");
        __builtin_amdgcn_sched_barrier(0);
        // step3: ds_write A(t+1) (loaded 2 iters ago; vmcnt above guarantees)
        if (t <= NKC - 2)
            *(bf16x8*)&Asm[(t + 1) & 1][aswz] = cvt8(regA[(t + 1) % 3][0], regA[(t + 1) % 3][1]);
        // step4+5: LDS flush + entry barrier
        asm volatile("s_waitcnt lgkmcnt(0)" ::: "memory");
        __builtin_amdgcn_sched_barrier(0);
        __builtin_amdgcn_s_barrier();
        __builtin_amdgcn_sched_barrier(0);
        // step6: compute on Asm[t&1], Bsm[t%3]
        {
            bf16x8 af[2], bfr[8];
#pragma unroll
            for (int mf = 0; mf < 2; ++mf) {
                int row = wr * 32 + mf * 16 + ln;
                af[mf] = *(const bf16x8*)&Asm[t & 1][row * 40 + q * 8];
            }
#pragma unroll
            for (int nf = 0; nf < 8; ++nf) {
                int row = wc * 128 + nf * 16 + ln;
                int u = q ^ ((l >> 1) & 3);
                bfr[nf] = *(const bf16x8*)&Bsm[t % 3][row * KC + u * 8];
            }
#pragma unroll
            for (int mf = 0; mf < 2; ++mf)
#pragma unroll
                for (int nf = 0; nf < 8; ++nf)
                    acc[mf][nf] = __builtin_amdgcn_mfma_f32_16x16x32_bf16(
                        af[mf], bfr[nf], acc[mf][nf], 0, 0, 0);
        }
        __builtin_amdgcn_sched_barrier(0);
        // step7: exit barrier (protects buffer reuse by next iter's issues)
        __builtin_amdgcn_s_barrier();
        __builtin_amdgcn_sched_barrier(0);
    }
#undef ISSUE_A
#undef ISSUE_B

    // epilogue: + hproj, tanh, dot v, 16-lane reduce
    float vv[8];
#pragma unroll
    for (int nf = 0; nf < 8; ++nf) vv[nf] = vvec[wc * 128 + nf * 16 + ln];
    const float* hp = hproj + b * HID;

#pragma unroll
    for (int mf = 0; mf < 2; ++mf) {
#pragma unroll
        for (int r = 0; r < 4; ++r) {
            int row = wr * 32 + mf * 16 + q * 4 + r;
            float p = 0.0f;
#pragma unroll
            for (int nf = 0; nf < 8; ++nf) {
                int col = wc * 128 + nf * 16 + ln;
                p += vv[nf] * ftanh(acc[mf][nf][r] + hp[col]);
            }
#pragma unroll
            for (int off = 8; off >= 1; off >>= 1) p += __shfl_xor(p, off);
            if (ln == 0) epart[row][wc] = p;
        }
    }
    __syncthreads();

    // chunk softmax partial (one wave)
    if (tid < 64) {
        int s = s0 + tid;
        float es = (s < SS) ? (epart[tid][0] + epart[tid][1]) : -1e30f;
        float m = es;
#pragma unroll
        for (int off = 32; off >= 1; off >>= 1) m = fmaxf(m, __shfl_xor(m, off));
        float p = __expf(es - m);
        ps[tid] = p;
        float sum = p;
#pragma unroll
        for (int off = 32; off >= 1; off >>= 1) sum += __shfl_xor(sum, off);
        if (tid == 0) {
            mls[(b * NCHK + chk) * 2 + 0] = m;
            mls[(b * NCHK + chk) * 2 + 1] = sum;
        }
    }
    __syncthreads();

    // chunk context partial
    const float* ep = enc + (size_t)(brow0 + s0) * F2H;
    const int smax = (SS - s0 < CH) ? (SS - s0) : CH;
    float c0 = 0.f, c1 = 0.f;
    for (int s = 0; s < smax; s += 4) {
#pragma unroll
        for (int q2 = 0; q2 < 4; ++q2) {
            float p = ps[s + q2];
            c0 += p * ep[(size_t)(s + q2) * F2H + tid];
            c1 += p * ep[(size_t)(s + q2) * F2H + tid + 256];
        }
    }
    ctxp[(size_t)(b * NCHK + chk) * F2H + tid] = c0;
    ctxp[(size_t)(b * NCHK + chk) * F2H + tid + 256] = c1;
}

// ---------------- K3: combine chunks + concat + projection ----------------
__global__ __launch_bounds__(256) void k_comb(
    const float* __restrict__ ctxp, const float* __restrict__ mls,
    const float* __restrict__ hvals, const float* __restrict__ proj_W,
    const float* __restrict__ proj_b, float* __restrict__ catp)
{
    const int b = blockIdx.x;
    const int j = threadIdx.x;
    __shared__ float cat[768];

    float m[NCHK], lv[NCHK];
#pragma unroll
    for (int c = 0; c < NCHK; ++c) {
        m[c]  = mls[(b * NCHK + c) * 2 + 0];
        lv[c] = mls[(b * NCHK + c) * 2 + 1];
    }
    float ms = m[0];
#pragma unroll
    for (int c = 1; c < NCHK; ++c) ms = fmaxf(ms, m[c]);
    float wgt[NCHK], L = 0.f;
#pragma unroll
    for (int c = 0; c < NCHK; ++c) { wgt[c] = __expf(m[c] - ms); L += lv[c] * wgt[c]; }
    float inv = 1.0f / L;

#pragma unroll
    for (int p = 0; p < 2; ++p) {
        int f = j + p * 256;
        float s = 0.f;
#pragma unroll
        for (int c = 0; c < NCHK; ++c) s += ctxp[((size_t)(b * NCHK + c)) * F2H + f] * wgt[c];
        cat[f] = s * inv;
    }
    cat[F2H + j] = hvals[b * HID + j];
    __syncthreads();

    float acc = proj_b[j];
    const float* wr = proj_W + j * 768;
#pragma unroll 8
    for (int k = 0; k < 768; k += 4) {
        float4 wv = *(const float4*)&wr[k];
        acc += cat[k] * wv.x + cat[k + 1] * wv.y + cat[k + 2] * wv.z + cat[k + 3] * wv.w;
    }
    catp[b * HID + j] = acc;
}

// ---------------- K6: output GEMM, v-tile 64, full-row B preload ----------------
__global__ __launch_bounds__(256) void k_out(
    const float* __restrict__ catp, const float* __restrict__ out_W,
    const float* __restrict__ out_b, float* __restrict__ wd)
{
    __shared__ ushort Cs[64 * 256];

    const int tid = threadIdx.x;
    const int l = tid & 63;
    const int w = tid >> 6;
    const int q = l >> 4;
    const int ln = l & 15;

    const int v = blockIdx.x * 64 + w * 16 + ln;
    const int vr = v < VOC ? v : VOC - 1;
    const float* pw = out_W + (size_t)vr * HID + q * 8;

    float4 wreg[16];
#pragma unroll
    for (int s = 0; s < 8; ++s) {
        wreg[2 * s]     = *(const float4*)(pw + s * 32);
        wreg[2 * s + 1] = *(const float4*)(pw + s * 32 + 4);
    }

#pragma unroll
    for (int i = 0; i < 8; ++i) {
        int u = i * 256 + tid;
        int n = u >> 5, c16 = u & 31;
        const float4* src = (const float4*)&catp[n * HID + c16 * 8];
        float4 f0 = src[0], f1 = src[1];
        *(bf16x8*)&Cs[n * 256 + ((c16 ^ (n & 7)) * 8)] = cvt8(f0, f1);
    }
    __syncthreads();

    f32x4 acc[4];
#pragma unroll
    for (int af = 0; af < 4; ++af) acc[af] = (f32x4){0.f, 0.f, 0.f, 0.f};

#pragma unroll
    for (int s = 0; s < 8; ++s) {
        bf16x8 bfr = cvt8(wreg[2 * s], wreg[2 * s + 1]);
#pragma unroll
        for (int af = 0; af < 4; ++af) {
            int row = af * 16 + ln;
            int c16 = (s * 4 + q) ^ (row & 7);
            bf16x8 a = *(const bf16x8*)&Cs[row * 256 + c16 * 8];
            acc[af] = __builtin_amdgcn_mfma_f32_16x16x32_bf16(a, bfr, acc[af], 0, 0, 0);
        }
    }

    if (v < VOC) {
        float bias = out_b[v];
#pragma unroll
        for (int af = 0; af < 4; ++af) {
            int b = af * 16 + q * 4;
#pragma unroll
            for (int r = 0; r < 4; ++r)
                wd[(size_t)(b + r) * VOC + v] = acc[af][r] + bias;
        }
    }
}

extern "C" void kernel_launch(void* const* d_in, const int* in_sizes, int n_in,
                              void* d_out, int out_size, void* d_ws, size_t ws_size,
                              hipStream_t stream) {
    const int*   word   = (const int*)  d_in[0];
    const float* hidden = (const float*)d_in[1];
    const float* cell   = (const float*)d_in[2];
    const float* enc    = (const float*)d_in[3];
    const float* embed  = (const float*)d_in[5];
    const float* W_ih   = (const float*)d_in[6];
    const float* W_hh   = (const float*)d_in[7];
    const float* b_ih   = (const float*)d_in[8];
    const float* b_hh   = (const float*)d_in[9];
    const float* attn_W = (const float*)d_in[10];
    const float* attn_b = (const float*)d_in[11];
    const float* vvec   = (const float*)d_in[12];
    const float* proj_W = (const float*)d_in[13];
    const float* proj_b = (const float*)d_in[14];
    const float* out_W  = (const float*)d_in[15];
    const float* out_b  = (const float*)d_in[16];

    float* wd  = (float*)d_out;
    float* h_o = wd + (size_t)BB * VOC;
    float* c_o = h_o + BB * HID;

    float* ws    = (float*)d_ws;
    float* part  = ws;                          // 262144
    float* hproj = part + 262144;               // 16384
    float* catp  = hproj + 16384;               // 16384
    float* ctxp  = catp + 16384;                // 64*7*512 = 229376
    float* mls   = ctxp + 229376;               // 896
    ushort* wenc_bf = (ushort*)(mls + 896);     // 131072 ushorts

    k_gates<<<dim3(16, 5), 256, 0, stream>>>(word, hidden, embed, W_ih, W_hh, part, attn_W, wenc_bf);
    k_lstm<<<64, 256, 0, stream>>>(part, cell, b_ih, b_hh, attn_W, attn_b, h_o, c_o, hproj);
    k_attn<<<BB * NCHK, 256, 0, stream>>>(enc, wenc_bf, hproj, vvec, ctxp, mls);
    k_comb<<<64, 256, 0, stream>>>(ctxp, mls, h_o, proj_W, proj_b, catp);
    k_out<<<782, 256, 0, stream>>>(catp, out_W, out_b, wd);
}